// Round 10
// baseline (548.707 us; speedup 1.0000x reference)
//
#include <hip/hip_runtime.h>

#define NC 512   // N_CLUSTERS

// ===========================================================================
// Merged pre-pass: blocks 0..63 transpose conv_lut, 64..127 fc_lut
// (transpose verified R3/R5/R6), blocks 128..639 discretize (verified
// R1/R5/R6). LDS unioned via char buffer.
// ===========================================================================
__global__ __launch_bounds__(256) void k_pre(
    const int* __restrict__ srcA, unsigned short* __restrict__ dstA,
    const int* __restrict__ srcB, unsigned short* __restrict__ dstB,
    const float* __restrict__ x, const float* __restrict__ cent,
    unsigned short* __restrict__ outsym)
{
    __shared__ __align__(16) char smem[64 * 65 * 2];   // 8320 B
    int tid = threadIdx.x;
    if (blockIdx.x < 128) {
        unsigned short (*tile)[65] = (unsigned short(*)[65])smem;
        int bid = blockIdx.x & 63;
        const int* src = (blockIdx.x < 64) ? srcA : srcB;
        unsigned short* dst = (blockIdx.x < 64) ? dstA : dstB;
        int tx = bid % 8, ty = bid / 8;
        int lane = tid & 63, grp = tid >> 6;
        for (int r = grp * 16; r < grp * 16 + 16; ++r)
            tile[r][lane] = (unsigned short)src[(ty * 64 + r) * NC + tx * 64 + lane];
        __syncthreads();
        for (int r = grp * 16; r < grp * 16 + 16; ++r)
            dst[(tx * 64 + r) * NC + ty * 64 + lane] = tile[lane][r];
    } else {
        float* c = (float*)smem;
        for (int i = tid; i < NC; i += 256) c[i] = cent[i];
        __syncthreads();
        int id = (blockIdx.x - 128) * 256 + tid;   // 131072 exact
        float px = x[id];
        float best = fabsf(px - c[0]);
        int bi = 0;
        for (int k = 1; k < NC; ++k) {
            float d = fabsf(px - c[k]);
            if (d < best) { best = d; bi = k; }
        }
        outsym[id] = (unsigned short)bi;
    }
}

// ===========================================================================
// 32-bin-window scanner (R6-verified EXACT revert — R9's prefetch/leader
// variants regressed and are dropped). SoA columns, element stride STRIDE.
// Redundant sub-lanes run identical state; far-insert plain RMW from r lanes
// writes same value (verified). Window loaded once (chunk monotone) =>
// stored mask exact. Pop budget exact => ensure() bounded.
// ===========================================================================
template<int STRIDE>
struct ScanL {
    uint32_t* col;     // bins + colidx; element stride STRIDE words
    uint64_t w0, w1;   // current 32-bin window (128b of nibble counts)
    uint32_t mask;     // bit k <=> bin (chunk*32+k) nonzero
    int chunk;

    __device__ inline void init(uint32_t* c) { col = c; mask = 0; chunk = -1; }
    __device__ inline void load() {
        uint32_t a0 = col[(chunk * 4 + 0) * STRIDE];
        uint32_t a1 = col[(chunk * 4 + 1) * STRIDE];
        uint32_t a2 = col[(chunk * 4 + 2) * STRIDE];
        uint32_t a3 = col[(chunk * 4 + 3) * STRIDE];
        mask = col[(64 + chunk) * STRIDE];      // precomputed window mask
        w0 = ((uint64_t)a1 << 32) | a0;
        w1 = ((uint64_t)a3 << 32) | a2;
    }
    __device__ inline void ensure() { while (mask == 0) { ++chunk; load(); } }
    __device__ inline int  peek()   { ensure(); return chunk * 32 + (int)__builtin_ctz(mask); }
    __device__ inline void consume_min() {          // precondition: mask != 0
        int k = (int)__builtin_ctz(mask);
        int sh = (k & 15) << 2;
        bool hi = k >= 16;
        uint64_t cw = hi ? w1 : w0;
        uint32_t cnt = (uint32_t)(cw >> sh) & 0xFu;
        cw -= (1ull << sh);
        if (hi) w1 = cw; else w0 = cw;
        if (cnt == 1) mask &= ~(1u << k);
    }
    __device__ inline int pop() { int v = peek(); consume_min(); return v; }
    __device__ inline void insert(int v) {          // precondition: v >= chunk*32
        int rel = v - chunk * 32;
        if (rel < 32) {
            int sh = (rel & 15) << 2;
            bool hi = rel >= 16;
            uint64_t cw = hi ? w1 : w0;
            cw += (1ull << sh);
            if (hi) w1 = cw; else w0 = cw;
            mask |= (1u << rel);
        } else {
            // redundant sub-lanes: same old, same new => plain RMW safe
            col[(v >> 3) * STRIDE] += (1u << ((v & 7) << 2));
            col[(64 + (v >> 5)) * STRIDE] |= (1u << (v & 31));
        }
    }
};

// ===========================================================================
// Cooperative symbolic conv (R6-exact). INST chains per 64-thread block,
// r=64/INST redundant sub-lanes. conv2 INST=16 (r=4); conv1 INST=64 (r=1).
// ===========================================================================
template<typename IT, typename OT, bool KMAJOR, int INST,
         int CIN, int CO, int IH, int IW, int OH, int OW>
__device__ __forceinline__ void conv_body(
    const IT* __restrict__ in_sym,              // (B, IH, IW, CIN)
    const int* __restrict__ wsym,               // (25*CIN, CO)
    const unsigned short* __restrict__ convT,   // (NC, NC) [w][s]
    const int* __restrict__ add_lut,            // (NC, NC)
    const int* __restrict__ bias_lut,           // (NC, CO)
    const int* __restrict__ relu_lut,           // (NC,)
    OT* __restrict__ out)
{
    constexpr int N    = 25 * CIN;
    constexpr int SUB  = 64 / INST;
    constexpr int PPI  = OH * OW;
    constexpr int BPC  = (128 * PPI) / INST;    // blocks per co (exact)
    __shared__ uint32_t bins[80 * INST];
    int tid = threadIdx.x;
    int il  = tid % INST;                       // chain-in-block
    int sub = tid / INST;                       // redundancy/role index

    for (int i = tid; i < 80 * INST; i += 64) bins[i] = 0u;

    int posg = blockIdx.x % BPC;
    int co   = blockIdx.x / BPC;                // block-uniform
    int pos  = posg * INST + il;
    int b  = pos / PPI;
    int yx = pos % PPI;
    int oy = yx / OW, ox = yx % OW;
    __syncthreads();                            // zero visible

#pragma unroll 4
    for (int n = sub; n < N; n += SUB) {        // subs split the N items
        int i   = n / (5 * CIN);
        int rem = n % (5 * CIN);
        int j   = rem / CIN;
        int c   = rem % CIN;
        int s = (int)in_sym[((b * IH + (oy * 2 + i)) * IW + (ox * 2 + j)) * CIN + c];
        int w = wsym[n * CO + co];
        int g = convT[w * NC + s];
        atomicAdd(&bins[(g >> 3) * INST + il], 1u << ((g & 7) << 2));   // ds_add no-ret
        atomicOr (&bins[(64 + (g >> 5)) * INST + il], 1u << (g & 31));  // window mask
    }
    __syncthreads();                            // build drained before fold

    // Fold (bit-identical chain semantics; r sub-lanes lockstep per chain).
    ScanL<INST> sc; sc.init(bins + il);
    int t = sc.pop();
    int u = sc.pop();
    int v = sc.pop();
    int t2 = add_lut[u * NC + t];               // load for j=1
#pragma unroll 1
    for (int j = 1; j <= N - 3; ++j) {
        int bb = sc.pop();                      // refill: overlaps in-flight load
        bool cA = (t2 <= v);                    // t2 arrives here (vmcnt wait)
        bool cC = (t2 > bb);                    // cC implies !cA (v <= bb)
        t = cA ? t2 : v;
        u = cA ? v : (cC ? bb : t2);
        int t2n = add_lut[u * NC + t];          // issue next load ASAP
        __builtin_amdgcn_sched_barrier(0);      // pin load above pq work
        if (cC) { sc.insert(t2); v = sc.pop(); }   // hidden under next load
        else    v = bb;
        t2 = t2n;
    }
    t = t2;                                     // j = N-2
    t = add_lut[v * NC + t];                    // j = N-1
    if (sub == 0) {
        int r = relu_lut[bias_lut[t * CO + co]];
        if (KMAJOR) out[(co * PPI + yx) * 128 + b] = (OT)r;   // k-major for fc1
        else        out[pos * CO + co] = (OT)r;
    }
}

__global__ __launch_bounds__(64) void k_conv1(
    const unsigned short* in, const int* wsym, const unsigned short* convT,
    const int* add_lut, const int* bias, const int* relu, unsigned short* out)
{
    conv_body<unsigned short, unsigned short, false, 64, 1, 6, 32, 32, 14, 14>(
        in, wsym, convT, add_lut, bias, relu, out);
}

__global__ __launch_bounds__(64) void k_conv2(
    const unsigned short* in, const int* wsym, const unsigned short* convT,
    const int* add_lut, const int* bias, const int* relu, int* out)
{
    conv_body<unsigned short, int, true, 16, 6, 16, 14, 14, 5, 5>(
        in, wsym, convT, add_lut, bias, relu, out);
}

// ===========================================================================
// Cooperative symbolic FC (R6-exact). INST=8 chains per 64-thread block,
// r=8 sub-lanes => 8 distinct add_lut lines per fold gather.
// ===========================================================================
template<int M, int K>
__device__ __forceinline__ void fc_body(
    const int* __restrict__ in_sym,    // (K, 128) k-major
    const int* __restrict__ wsym,      // (M, K)
    const unsigned short* __restrict__ fcT,  // (NC, NC) [w][x]
    const int* __restrict__ add_lut,   // (NC, NC)
    const int* __restrict__ bias_lut,  // (NC, M)
    const int* __restrict__ relu_lut,  // (NC,)
    int* __restrict__ out)             // (M, 128) m-major
{
    constexpr int INST = 8;
    constexpr int SUB  = 8;
    __shared__ uint32_t bins[80 * INST];
    int tid = threadIdx.x;
    int il  = tid % INST;
    int sub = tid / INST;

    for (int i = tid; i < 80 * INST; i += 64) bins[i] = 0u;

    int m  = blockIdx.x / 16;                  // block-uniform
    int bg = blockIdx.x % 16;
    int b  = bg * INST + il;
    __syncthreads();

#pragma unroll 4
    for (int k = sub; k < K; k += SUB) {
        int x = in_sym[k * 128 + b];
        int w = wsym[m * K + k];
        int g = fcT[w * NC + x];
        atomicAdd(&bins[(g >> 3) * INST + il], 1u << ((g & 7) << 2));
        atomicOr (&bins[(64 + (g >> 5)) * INST + il], 1u << (g & 31));
    }
    __syncthreads();

    // Pipelined ascending-pop fold: pop s+1 during load s.
    ScanL<INST> sc; sc.init(bins + il);
    int t = sc.pop();
    int x = sc.pop();
    int t2 = add_lut[x * NC + t];              // load s=1
#pragma unroll 1
    for (int s = 1; s < K - 1; ++s) {
        int xn = sc.pop();                     // overlaps in-flight load
        t = t2;                                // vmcnt wait lands here
        t2 = add_lut[xn * NC + t];             // issue next load
        __builtin_amdgcn_sched_barrier(0);     // pin load issue in-loop
    }
    t = t2;
    if (sub == 0)
        out[m * 128 + b] = relu_lut[bias_lut[t * M + m]];
}

__global__ __launch_bounds__(64) void k_fc1(
    const int* in, const int* wsym, const unsigned short* fcT,
    const int* add_lut, const int* bias, const int* relu, int* out)
{
    fc_body<120, 400>(in, wsym, fcT, add_lut, bias, relu, out);
}

__global__ __launch_bounds__(64) void k_fc2(
    const int* in, const int* wsym, const unsigned short* fcT,
    const int* add_lut, const int* bias, const int* relu, int* out)
{
    fc_body<84, 120>(in, wsym, fcT, add_lut, bias, relu, out);
}

// ===========================================================================
// Head: feats = centroid[sym], logits @ W^T + b, softmax. Reads m-major f2.
// ===========================================================================
__global__ __launch_bounds__(64) void k_head(
    const int* __restrict__ f2m,       // (84, 128) m-major
    const float* __restrict__ cent,    // (NC,)
    const float* __restrict__ w,       // (10, 84)
    const float* __restrict__ bias,    // (10,)
    float* __restrict__ out)           // (128, 10)
{
    int b = blockIdx.x * 64 + threadIdx.x;
    float acc[10];
#pragma unroll
    for (int o = 0; o < 10; ++o) acc[o] = bias[o];
    for (int k = 0; k < 84; ++k) {
        float f = cent[f2m[k * 128 + b]];      // coalesced
#pragma unroll
        for (int o = 0; o < 10; ++o) acc[o] += f * w[o * 84 + k];
    }
    float mx = acc[0];
#pragma unroll
    for (int o = 1; o < 10; ++o) mx = fmaxf(mx, acc[o]);
    float s = 0.f;
#pragma unroll
    for (int o = 0; o < 10; ++o) { acc[o] = expf(acc[o] - mx); s += acc[o]; }
    float inv = 1.f / s;
#pragma unroll
    for (int o = 0; o < 10; ++o) out[b * 10 + o] = acc[o] * inv;
}

// ===========================================================================
// DIAGNOSTIC SHADOWS (R10): conv2 geometry, real data, 80-link folds,
// write to spare ws scratch (not the graded output). Run AFTER k_head.
// MODE 0 = FULL   (exact conv fold, 80 links)        -> reference
// MODE 1 = NOPQ   (ascending pops only, same gather) -> Vf - V1 = pq cost
// MODE 2 = NOLOAD (full pq, t2=(u+t)&511, no mem)    -> Vf - V2 = load cost
// Pop budgets: M1: 2+80=82<=150; M0/M2: 3+80+balanced<=150 => no hang.
// insert precondition holds in M2: t2>bb>=chunk*32.
// ===========================================================================
template<int MODE>
__global__ __launch_bounds__(64) void k_shadow(
    const unsigned short* __restrict__ in_sym,   // c1o
    const int* __restrict__ wsym,                // c2f
    const unsigned short* __restrict__ convT,
    const int* __restrict__ add_lut,
    int* __restrict__ sout)
{
    constexpr int CIN = 6, CO = 16, IH = 14, IW = 14, OW = 5;
    constexpr int N = 150, INST = 16, SUB = 4, PPI = 25, BPC = 200;
    __shared__ uint32_t bins[80 * INST];
    int tid = threadIdx.x;
    int il  = tid % INST;
    int sub = tid / INST;

    for (int i = tid; i < 80 * INST; i += 64) bins[i] = 0u;

    int posg = blockIdx.x % BPC;
    int co   = blockIdx.x / BPC;
    int pos  = posg * INST + il;
    int b  = pos / PPI;
    int yx = pos % PPI;
    int oy = yx / OW, ox = yx % OW;
    __syncthreads();

#pragma unroll 4
    for (int n = sub; n < N; n += SUB) {         // build: identical to conv2
        int i   = n / (5 * CIN);
        int rem = n % (5 * CIN);
        int j   = rem / CIN;
        int c   = rem % CIN;
        int s = (int)in_sym[((b * IH + (oy * 2 + i)) * IW + (ox * 2 + j)) * CIN + c];
        int w = wsym[n * CO + co];
        int g = convT[w * NC + s];
        atomicAdd(&bins[(g >> 3) * INST + il], 1u << ((g & 7) << 2));
        atomicOr (&bins[(64 + (g >> 5)) * INST + il], 1u << (g & 31));
    }
    __syncthreads();

    ScanL<INST> sc; sc.init(bins + il);
    if (MODE == 1) {
        int t = sc.pop();
        int x = sc.pop();
        int t2 = add_lut[x * NC + t];
#pragma unroll 1
        for (int s = 1; s <= 80; ++s) {
            int xn = sc.pop();
            t = t2;
            t2 = add_lut[xn * NC + t];
            __builtin_amdgcn_sched_barrier(0);
        }
        if (sub == 0) sout[pos * CO + co] = t2;
    } else {
        int t = sc.pop();
        int u = sc.pop();
        int v = sc.pop();
        int t2 = (MODE == 0) ? add_lut[u * NC + t] : ((u + t) & 511);
#pragma unroll 1
        for (int j = 1; j <= 80; ++j) {
            int bb = sc.pop();
            bool cA = (t2 <= v);
            bool cC = (t2 > bb);
            t = cA ? t2 : v;
            u = cA ? v : (cC ? bb : t2);
            int t2n = (MODE == 0) ? add_lut[u * NC + t] : ((u + t) & 511);
            __builtin_amdgcn_sched_barrier(0);
            if (cC) { sc.insert(t2); v = sc.pop(); }
            else    v = bb;
            t2 = t2n;
        }
        if (sub == 0) sout[pos * CO + co] = t2;
    }
}

// ===========================================================================
extern "C" void kernel_launch(void* const* d_in, const int* in_sizes, int n_in,
                              void* d_out, int out_size, void* d_ws, size_t ws_size,
                              hipStream_t stream)
{
    const float* x_bat  = (const float*)d_in[0];
    const float* cent   = (const float*)d_in[1];
    const int* conv_lut = (const int*)d_in[2];
    const int* fc_lut   = (const int*)d_in[3];
    const int* add_lut  = (const int*)d_in[4];
    const int* relu_lut = (const int*)d_in[5];
    const int* c1_bias  = (const int*)d_in[6];
    const int* c2_bias  = (const int*)d_in[7];
    const int* f1_bias  = (const int*)d_in[8];
    const int* f2_bias  = (const int*)d_in[9];
    const int* c1f      = (const int*)d_in[10];
    const int* c2f      = (const int*)d_in[11];
    const int* f1f      = (const int*)d_in[12];
    const int* f2f      = (const int*)d_in[13];
    const float* fc3_w  = (const float*)d_in[14];
    const float* fc3_b  = (const float*)d_in[15];
    float* out = (float*)d_out;

    char* ws = (char*)d_ws;
    unsigned short* convT = (unsigned short*)(ws);            // 512 KB
    unsigned short* fcT   = (unsigned short*)(ws + 524288);   // 512 KB
    unsigned short* sym0  = (unsigned short*)(ws + 1048576);  // 256 KB
    unsigned short* c1o   = (unsigned short*)(ws + 1310720);  // 294 KB (b,14,14,6) u16
    int* c2o  = (int*)(ws + 1611776);                         // 200 KB (400,128) k-major
    int* f1o  = (int*)(ws + 1816576);                         //  60 KB (120,128) m-major
    int* f2o  = (int*)(ws + 1878016);                         //  42 KB (84,128)  m-major
    int* sout = (int*)(ws + 1921024);                         // 200 KB shadow scratch
    // peak ws ~2.03 MB (< proven 2.29 MB)

    // merged transpose (blocks 0..127) + discretize (blocks 128..639)
    k_pre<<<640, 256, 0, stream>>>(conv_lut, convT, fc_lut, fcT, x_bat, cent, sym0);
    // conv1: 6 co x 392 pos-groups = 2352 blocks (64 chains, r=1)
    k_conv1<<<2352, 64, 0, stream>>>(sym0, c1f, convT, add_lut, c1_bias, relu_lut, c1o);
    // conv2: 16 co x 200 pos-groups = 3200 blocks (16 chains, r=4)
    k_conv2<<<3200, 64, 0, stream>>>(c1o, c2f, convT, add_lut, c2_bias, relu_lut, c2o);
    // fc1: 120 m x 16 b-groups = 1920 blocks (8 chains, r=8)
    k_fc1<<<1920, 64, 0, stream>>>(c2o, f1f, fcT, add_lut, f1_bias, relu_lut, f1o);
    // fc2: 84 m x 16 b-groups = 1344 blocks
    k_fc2<<<1344, 64, 0, stream>>>(f1o, f2f, fcT, add_lut, f2_bias, relu_lut, f2o);
    k_head<<<2, 64, 0, stream>>>(f2o, cent, fc3_w, fc3_b, out);

    // --- diagnostic shadows (one-round ablation; see R10 notes) ---
    k_shadow<0><<<3200, 64, 0, stream>>>(c1o, c2f, convT, add_lut, sout);
    k_shadow<1><<<3200, 64, 0, stream>>>(c1o, c2f, convT, add_lut, sout);
    k_shadow<2><<<3200, 64, 0, stream>>>(c1o, c2f, convT, add_lut, sout);
}

// Round 11
// 380.448 us; speedup vs baseline: 1.4423x; 1.4423x over previous
//
#include <hip/hip_runtime.h>

#define NC 512   // N_CLUSTERS

// ===========================================================================
// Merged pre-pass: blocks 0..63 transpose conv_lut, 64..127 fc_lut
// (transpose verified R3/R5/R6), blocks 128..639 discretize (verified
// R1/R5/R6). LDS unioned via char buffer.
// ===========================================================================
__global__ __launch_bounds__(256) void k_pre(
    const int* __restrict__ srcA, unsigned short* __restrict__ dstA,
    const int* __restrict__ srcB, unsigned short* __restrict__ dstB,
    const float* __restrict__ x, const float* __restrict__ cent,
    unsigned short* __restrict__ outsym)
{
    __shared__ __align__(16) char smem[64 * 65 * 2];   // 8320 B
    int tid = threadIdx.x;
    if (blockIdx.x < 128) {
        unsigned short (*tile)[65] = (unsigned short(*)[65])smem;
        int bid = blockIdx.x & 63;
        const int* src = (blockIdx.x < 64) ? srcA : srcB;
        unsigned short* dst = (blockIdx.x < 64) ? dstA : dstB;
        int tx = bid % 8, ty = bid / 8;
        int lane = tid & 63, grp = tid >> 6;
        for (int r = grp * 16; r < grp * 16 + 16; ++r)
            tile[r][lane] = (unsigned short)src[(ty * 64 + r) * NC + tx * 64 + lane];
        __syncthreads();
        for (int r = grp * 16; r < grp * 16 + 16; ++r)
            dst[(tx * 64 + r) * NC + ty * 64 + lane] = tile[lane][r];
    } else {
        float* c = (float*)smem;
        for (int i = tid; i < NC; i += 256) c[i] = cent[i];
        __syncthreads();
        int id = (blockIdx.x - 128) * 256 + tid;   // 131072 exact
        float px = x[id];
        float best = fabsf(px - c[0]);
        int bi = 0;
        for (int k = 1; k < NC; ++k) {
            float d = fabsf(px - c[k]);
            if (d < best) { best = d; bi = k; }
        }
        outsym[id] = (unsigned short)bi;
    }
}

// ===========================================================================
// 32-bin-window scanner (R6-verified). SoA columns, element stride STRIDE.
// Redundant sub-lanes run identical state; far-insert plain RMW from r lanes
// writes same value (verified). Window loaded once (chunk monotone) =>
// stored mask exact. Pop budget exact => ensure() bounded.
// ===========================================================================
template<int STRIDE>
struct ScanL {
    uint32_t* col;     // bins + colidx; element stride STRIDE words
    uint64_t w0, w1;   // current 32-bin window (128b of nibble counts)
    uint32_t mask;     // bit k <=> bin (chunk*32+k) nonzero
    int chunk;

    __device__ inline void init(uint32_t* c) { col = c; mask = 0; chunk = -1; }
    __device__ inline void load() {
        uint32_t a0 = col[(chunk * 4 + 0) * STRIDE];
        uint32_t a1 = col[(chunk * 4 + 1) * STRIDE];
        uint32_t a2 = col[(chunk * 4 + 2) * STRIDE];
        uint32_t a3 = col[(chunk * 4 + 3) * STRIDE];
        mask = col[(64 + chunk) * STRIDE];      // precomputed window mask
        w0 = ((uint64_t)a1 << 32) | a0;
        w1 = ((uint64_t)a3 << 32) | a2;
    }
    __device__ inline void ensure() { while (mask == 0) { ++chunk; load(); } }
    __device__ inline int  peek()   { ensure(); return chunk * 32 + (int)__builtin_ctz(mask); }
    __device__ inline void consume_min() {          // precondition: mask != 0
        int k = (int)__builtin_ctz(mask);
        int sh = (k & 15) << 2;
        bool hi = k >= 16;
        uint64_t cw = hi ? w1 : w0;
        uint32_t cnt = (uint32_t)(cw >> sh) & 0xFu;
        cw -= (1ull << sh);
        if (hi) w1 = cw; else w0 = cw;
        if (cnt == 1) mask &= ~(1u << k);
    }
    __device__ inline int pop() { int v = peek(); consume_min(); return v; }
    __device__ inline void insert(int v) {          // precondition: v >= chunk*32
        int rel = v - chunk * 32;
        if (rel < 32) {
            int sh = (rel & 15) << 2;
            bool hi = rel >= 16;
            uint64_t cw = hi ? w1 : w0;
            cw += (1ull << sh);
            if (hi) w1 = cw; else w0 = cw;
            mask |= (1u << rel);
        } else {
            // redundant sub-lanes: same old, same new => plain RMW safe
            col[(v >> 3) * STRIDE] += (1u << ((v & 7) << 2));
            col[(64 + (v >> 5)) * STRIDE] |= (1u << (v & 31));
        }
    }
};

// ===========================================================================
// Cooperative symbolic conv (R6 structure + R11 speculative cC load).
// Fold identity: next address add_lut[u'*NC+t'] with (u',t') one of
//   cA: (v, t2)   cB: (t2, v)   cC: (bb, v)    [cC = t2 > bb, implies !cA]
// The cC address needs NO t2 => issue it at loop top, BEFORE the vmcnt wait
// on the in-flight t2 (compiler emits counted vmcnt(1)). When cC hits
// (common: t2 ~ uniform vs small ascending bb), the next link's load has a
// full link head start => consecutive cC links cost ~L/2. Miss = previous
// behavior + one wasted L2 read. Bit-exact: spec == add_lut[bb*NC+v].
// ===========================================================================
template<typename IT, typename OT, bool KMAJOR, int INST,
         int CIN, int CO, int IH, int IW, int OH, int OW>
__device__ __forceinline__ void conv_body(
    const IT* __restrict__ in_sym,              // (B, IH, IW, CIN)
    const int* __restrict__ wsym,               // (25*CIN, CO)
    const unsigned short* __restrict__ convT,   // (NC, NC) [w][s]
    const int* __restrict__ add_lut,            // (NC, NC)
    const int* __restrict__ bias_lut,           // (NC, CO)
    const int* __restrict__ relu_lut,           // (NC,)
    OT* __restrict__ out)
{
    constexpr int N    = 25 * CIN;
    constexpr int SUB  = 64 / INST;
    constexpr int PPI  = OH * OW;
    constexpr int BPC  = (128 * PPI) / INST;    // blocks per co (exact)
    __shared__ uint32_t bins[80 * INST];
    int tid = threadIdx.x;
    int il  = tid % INST;                       // chain-in-block
    int sub = tid / INST;                       // redundancy/role index

    for (int i = tid; i < 80 * INST; i += 64) bins[i] = 0u;

    int posg = blockIdx.x % BPC;
    int co   = blockIdx.x / BPC;                // block-uniform
    int pos  = posg * INST + il;
    int b  = pos / PPI;
    int yx = pos % PPI;
    int oy = yx / OW, ox = yx % OW;
    __syncthreads();                            // zero visible

#pragma unroll 4
    for (int n = sub; n < N; n += SUB) {        // subs split the N items
        int i   = n / (5 * CIN);
        int rem = n % (5 * CIN);
        int j   = rem / CIN;
        int c   = rem % CIN;
        int s = (int)in_sym[((b * IH + (oy * 2 + i)) * IW + (ox * 2 + j)) * CIN + c];
        int w = wsym[n * CO + co];
        int g = convT[w * NC + s];
        atomicAdd(&bins[(g >> 3) * INST + il], 1u << ((g & 7) << 2));   // ds_add no-ret
        atomicOr (&bins[(64 + (g >> 5)) * INST + il], 1u << (g & 31));  // window mask
    }
    __syncthreads();                            // build drained before fold

    // Fold (bit-identical chain semantics; r sub-lanes lockstep per chain).
    ScanL<INST> sc; sc.init(bins + il);
    int t = sc.pop();
    int u = sc.pop();
    int v = sc.pop();
    int t2 = add_lut[u * NC + t];               // load for j=1
#pragma unroll 1
    for (int j = 1; j <= N - 3; ++j) {
        int bb = sc.pop();                      // refill (t2-independent)
        int spec = add_lut[bb * NC + v];        // speculative cC load, pre-t2
        __builtin_amdgcn_sched_barrier(0);      // pin spec issue above t2 wait
        bool cA = (t2 <= v);                    // t2 arrives here (vmcnt(1))
        bool cC = (t2 > bb);                    // cC implies !cA (v <= bb)
        t = cA ? t2 : v;
        u = cA ? v : (cC ? bb : t2);
        if (cC) {
            sc.insert(t2); v = sc.pop();        // spec already in flight
            t2 = spec;
        } else {
            t2 = add_lut[u * NC + t];           // true load (spec wasted)
            v = bb;
        }
    }
    t = t2;                                     // j = N-2
    t = add_lut[v * NC + t];                    // j = N-1
    if (sub == 0) {
        int r = relu_lut[bias_lut[t * CO + co]];
        if (KMAJOR) out[(co * PPI + yx) * 128 + b] = (OT)r;   // k-major for fc1
        else        out[pos * CO + co] = (OT)r;
    }
}

__global__ __launch_bounds__(64) void k_conv1(
    const unsigned short* in, const int* wsym, const unsigned short* convT,
    const int* add_lut, const int* bias, const int* relu, unsigned short* out)
{
    conv_body<unsigned short, unsigned short, false, 64, 1, 6, 32, 32, 14, 14>(
        in, wsym, convT, add_lut, bias, relu, out);
}

__global__ __launch_bounds__(64) void k_conv2(
    const unsigned short* in, const int* wsym, const unsigned short* convT,
    const int* add_lut, const int* bias, const int* relu, int* out)
{
    conv_body<unsigned short, int, true, 16, 6, 16, 14, 14, 5, 5>(
        in, wsym, convT, add_lut, bias, relu, out);
}

// ===========================================================================
// Cooperative symbolic FC (R6-exact). INST=8 chains per 64-thread block,
// r=8 sub-lanes => 8 distinct add_lut lines per fold gather. No speculation
// possible (next address depends on t2 directly). fc1: 1920, fc2: 1344.
// ===========================================================================
template<int M, int K>
__device__ __forceinline__ void fc_body(
    const int* __restrict__ in_sym,    // (K, 128) k-major
    const int* __restrict__ wsym,      // (M, K)
    const unsigned short* __restrict__ fcT,  // (NC, NC) [w][x]
    const int* __restrict__ add_lut,   // (NC, NC)
    const int* __restrict__ bias_lut,  // (NC, M)
    const int* __restrict__ relu_lut,  // (NC,)
    int* __restrict__ out)             // (M, 128) m-major
{
    constexpr int INST = 8;
    constexpr int SUB  = 8;
    __shared__ uint32_t bins[80 * INST];
    int tid = threadIdx.x;
    int il  = tid % INST;
    int sub = tid / INST;

    for (int i = tid; i < 80 * INST; i += 64) bins[i] = 0u;

    int m  = blockIdx.x / 16;                  // block-uniform
    int bg = blockIdx.x % 16;
    int b  = bg * INST + il;
    __syncthreads();

#pragma unroll 4
    for (int k = sub; k < K; k += SUB) {
        int x = in_sym[k * 128 + b];
        int w = wsym[m * K + k];
        int g = fcT[w * NC + x];
        atomicAdd(&bins[(g >> 3) * INST + il], 1u << ((g & 7) << 2));
        atomicOr (&bins[(64 + (g >> 5)) * INST + il], 1u << (g & 31));
    }
    __syncthreads();

    // Pipelined ascending-pop fold: pop s+1 during load s.
    ScanL<INST> sc; sc.init(bins + il);
    int t = sc.pop();
    int x = sc.pop();
    int t2 = add_lut[x * NC + t];              // load s=1
#pragma unroll 1
    for (int s = 1; s < K - 1; ++s) {
        int xn = sc.pop();                     // overlaps in-flight load
        t = t2;                                // vmcnt wait lands here
        t2 = add_lut[xn * NC + t];             // issue next load
        __builtin_amdgcn_sched_barrier(0);     // pin load issue in-loop
    }
    t = t2;
    if (sub == 0)
        out[m * 128 + b] = relu_lut[bias_lut[t * M + m]];
}

__global__ __launch_bounds__(64) void k_fc1(
    const int* in, const int* wsym, const unsigned short* fcT,
    const int* add_lut, const int* bias, const int* relu, int* out)
{
    fc_body<120, 400>(in, wsym, fcT, add_lut, bias, relu, out);
}

__global__ __launch_bounds__(64) void k_fc2(
    const int* in, const int* wsym, const unsigned short* fcT,
    const int* add_lut, const int* bias, const int* relu, int* out)
{
    fc_body<84, 120>(in, wsym, fcT, add_lut, bias, relu, out);
}

// ===========================================================================
// Head: feats = centroid[sym], logits @ W^T + b, softmax. Reads m-major f2.
// ===========================================================================
__global__ __launch_bounds__(64) void k_head(
    const int* __restrict__ f2m,       // (84, 128) m-major
    const float* __restrict__ cent,    // (NC,)
    const float* __restrict__ w,       // (10, 84)
    const float* __restrict__ bias,    // (10,)
    float* __restrict__ out)           // (128, 10)
{
    int b = blockIdx.x * 64 + threadIdx.x;
    float acc[10];
#pragma unroll
    for (int o = 0; o < 10; ++o) acc[o] = bias[o];
    for (int k = 0; k < 84; ++k) {
        float f = cent[f2m[k * 128 + b]];      // coalesced
#pragma unroll
        for (int o = 0; o < 10; ++o) acc[o] += f * w[o * 84 + k];
    }
    float mx = acc[0];
#pragma unroll
    for (int o = 1; o < 10; ++o) mx = fmaxf(mx, acc[o]);
    float s = 0.f;
#pragma unroll
    for (int o = 0; o < 10; ++o) { acc[o] = expf(acc[o] - mx); s += acc[o]; }
    float inv = 1.f / s;
#pragma unroll
    for (int o = 0; o < 10; ++o) out[b * 10 + o] = acc[o] * inv;
}

// ===========================================================================
extern "C" void kernel_launch(void* const* d_in, const int* in_sizes, int n_in,
                              void* d_out, int out_size, void* d_ws, size_t ws_size,
                              hipStream_t stream)
{
    const float* x_bat  = (const float*)d_in[0];
    const float* cent   = (const float*)d_in[1];
    const int* conv_lut = (const int*)d_in[2];
    const int* fc_lut   = (const int*)d_in[3];
    const int* add_lut  = (const int*)d_in[4];
    const int* relu_lut = (const int*)d_in[5];
    const int* c1_bias  = (const int*)d_in[6];
    const int* c2_bias  = (const int*)d_in[7];
    const int* f1_bias  = (const int*)d_in[8];
    const int* f2_bias  = (const int*)d_in[9];
    const int* c1f      = (const int*)d_in[10];
    const int* c2f      = (const int*)d_in[11];
    const int* f1f      = (const int*)d_in[12];
    const int* f2f      = (const int*)d_in[13];
    const float* fc3_w  = (const float*)d_in[14];
    const float* fc3_b  = (const float*)d_in[15];
    float* out = (float*)d_out;

    char* ws = (char*)d_ws;
    unsigned short* convT = (unsigned short*)(ws);            // 512 KB
    unsigned short* fcT   = (unsigned short*)(ws + 524288);   // 512 KB
    unsigned short* sym0  = (unsigned short*)(ws + 1048576);  // 256 KB
    unsigned short* c1o   = (unsigned short*)(ws + 1310720);  // 294 KB (b,14,14,6) u16
    int* c2o = (int*)(ws + 1611776);                          // 200 KB (400,128) k-major
    int* f1o = (int*)(ws + 1816576);                          //  60 KB (120,128) m-major
    int* f2o = (int*)(ws + 1878016);                          //  42 KB (84,128)  m-major
    // peak ws ~1.92 MB

    // merged transpose (blocks 0..127) + discretize (blocks 128..639)
    k_pre<<<640, 256, 0, stream>>>(conv_lut, convT, fc_lut, fcT, x_bat, cent, sym0);
    // conv1: 6 co x 392 pos-groups = 2352 blocks (64 chains, r=1)
    k_conv1<<<2352, 64, 0, stream>>>(sym0, c1f, convT, add_lut, c1_bias, relu_lut, c1o);
    // conv2: 16 co x 200 pos-groups = 3200 blocks (16 chains, r=4)
    k_conv2<<<3200, 64, 0, stream>>>(c1o, c2f, convT, add_lut, c2_bias, relu_lut, c2o);
    // fc1: 120 m x 16 b-groups = 1920 blocks (8 chains, r=8)
    k_fc1<<<1920, 64, 0, stream>>>(c2o, f1f, fcT, add_lut, f1_bias, relu_lut, f1o);
    // fc2: 84 m x 16 b-groups = 1344 blocks
    k_fc2<<<1344, 64, 0, stream>>>(f1o, f2f, fcT, add_lut, f2_bias, relu_lut, f2o);
    k_head<<<2, 64, 0, stream>>>(f2o, cent, fc3_w, fc3_b, out);
}